// Round 3
// baseline (101.067 us; speedup 1.0000x reference)
//
#include <hip/hip_runtime.h>

// x[C=64][H=512][W=512] fp32 -> out[C=64][OH=256][OW=256] fp32.
// 2x2 stride-2 "MaxNetwork" pooling:
//   pairmax(a,b) = relu(relu(a-b) + relu(b)) = max(a-b,0) + max(b,0)
// Window order (0,0),(0,1),(1,0),(1,1):
//   m1 = pairmax(w00,w01); m2 = pairmax(w10,w11); out = pairmax(m1,m2).
//
// Memory-bound: 64 MB in + 16 MB out = 80 MB @ ~6.3 TB/s => ~13 us floor.
// R1 profile: kernel below top-5 (all 43us harness poison fills) => kernel <42us;
// bench dur_us ~94 is dominated by harness reset dispatches.

#define C_  64
#define W_  512
#define OH_ 256
#define OW_ 256

// Native clang vector type — required for __builtin_nontemporal_* (HIP's
// float4 is a class and is rejected by the builtin).
typedef float f32x4 __attribute__((ext_vector_type(4)));

__device__ __forceinline__ float pairmax(float a, float b) {
    return fmaxf(a - b, 0.0f) + fmaxf(b, 0.0f);
}

// One thread -> 4 output pixels. Loads: 4x float4 nontemporal (2 rows x 8 cols).
// Store: 1x float4 nontemporal. 4096 blocks x 256 threads.
__global__ __launch_bounds__(256) void maxnet_pool_kernel(
        const float* __restrict__ x, float* __restrict__ out) {
    const int tid  = blockIdx.x * blockDim.x + threadIdx.x; // [0, C*OH*OW/4)
    const int ow4  = tid & (OW_ / 4 - 1);   // which quad of output cols (0..63)
    const int rest = tid >> 6;              // c*OH + oh
    // Input row = c*H + 2*oh = 2*(c*OH + oh) = 2*rest; col = 8*ow4.
    const int base = (rest << 1) * W_ + (ow4 << 3);

    const f32x4* p0 = reinterpret_cast<const f32x4*>(x + base);
    const f32x4* p1 = reinterpret_cast<const f32x4*>(x + base + W_);
    const f32x4 a0 = __builtin_nontemporal_load(p0);      // row0 cols 0..3
    const f32x4 a1 = __builtin_nontemporal_load(p0 + 1);  // row0 cols 4..7
    const f32x4 b0 = __builtin_nontemporal_load(p1);      // row1 cols 0..3
    const f32x4 b1 = __builtin_nontemporal_load(p1 + 1);  // row1 cols 4..7

    f32x4 o;
    o.x = pairmax(pairmax(a0.x, a0.y), pairmax(b0.x, b0.y));
    o.y = pairmax(pairmax(a0.z, a0.w), pairmax(b0.z, b0.w));
    o.z = pairmax(pairmax(a1.x, a1.y), pairmax(b1.x, b1.y));
    o.w = pairmax(pairmax(a1.z, a1.w), pairmax(b1.z, b1.w));

    // out index: rest*OW + 4*ow4 = 4*tid (contiguous).
    __builtin_nontemporal_store(o, reinterpret_cast<f32x4*>(out) + tid);
}

extern "C" void kernel_launch(void* const* d_in, const int* in_sizes, int n_in,
                              void* d_out, int out_size, void* d_ws, size_t ws_size,
                              hipStream_t stream) {
    const float* x = (const float*)d_in[0];
    float* out = (float*)d_out;
    const int n_threads = C_ * OH_ * (OW_ / 4);  // 1,048,576
    const int block = 256;
    const int grid = n_threads / block;          // 4096
    maxnet_pool_kernel<<<grid, block, 0, stream>>>(x, out);
}

// Round 4
// 95.132 us; speedup vs baseline: 1.0624x; 1.0624x over previous
//
#include <hip/hip_runtime.h>

// x[C=64][H=512][W=512] fp32 -> out[C=64][OH=256][OW=256] fp32.
// 2x2 stride-2 "MaxNetwork" pooling:
//   pairmax(a,b) = relu(relu(a-b) + relu(b)) = max(a-b,0) + max(b,0)
// Window order (0,0),(0,1),(1,0),(1,1):
//   m1 = pairmax(w00,w01); m2 = pairmax(w10,w11); out = pairmax(m1,m2).
//
// NOTE (R3 post-mortem): the harness's d_in restore warms the 256 MB L3 with
// the whole 64 MB input, so CACHED loads beat HBM roofline. Nontemporal
// loads bypassed L3 and regressed dur_us 94->101 us. Keep normal loads.
// Effective kernel time ~7-9 us; bench dur_us is dominated by ~83 us of
// harness poison-fill dispatches.

#define C_  64
#define W_  512
#define OH_ 256
#define OW_ 256

__device__ __forceinline__ float pairmax(float a, float b) {
    return fmaxf(a - b, 0.0f) + fmaxf(b, 0.0f);
}

// One thread -> 4 output pixels. Loads: 4x float4 cached (2 rows x 8 cols).
// Store: 1x float4. 4096 blocks x 256 threads.
__global__ __launch_bounds__(256) void maxnet_pool_kernel(
        const float* __restrict__ x, float* __restrict__ out) {
    const int tid  = blockIdx.x * blockDim.x + threadIdx.x; // [0, C*OH*OW/4)
    const int ow4  = tid & (OW_ / 4 - 1);   // which quad of output cols (0..63)
    const int rest = tid >> 6;              // c*OH + oh
    // Input row = c*H + 2*oh = 2*(c*OH + oh) = 2*rest; col = 8*ow4.
    const int base = (rest << 1) * W_ + (ow4 << 3);

    const float4 a0 = *reinterpret_cast<const float4*>(x + base);           // row0 0..3
    const float4 a1 = *reinterpret_cast<const float4*>(x + base + 4);       // row0 4..7
    const float4 b0 = *reinterpret_cast<const float4*>(x + base + W_);      // row1 0..3
    const float4 b1 = *reinterpret_cast<const float4*>(x + base + W_ + 4);  // row1 4..7

    float4 o;
    o.x = pairmax(pairmax(a0.x, a0.y), pairmax(b0.x, b0.y));
    o.y = pairmax(pairmax(a0.z, a0.w), pairmax(b0.z, b0.w));
    o.z = pairmax(pairmax(a1.x, a1.y), pairmax(b1.x, b1.y));
    o.w = pairmax(pairmax(a1.z, a1.w), pairmax(b1.z, b1.w));

    // out index: rest*OW + 4*ow4 = 4*tid (contiguous).
    *(reinterpret_cast<float4*>(out) + tid) = o;
}

extern "C" void kernel_launch(void* const* d_in, const int* in_sizes, int n_in,
                              void* d_out, int out_size, void* d_ws, size_t ws_size,
                              hipStream_t stream) {
    const float* x = (const float*)d_in[0];
    float* out = (float*)d_out;
    const int n_threads = C_ * OH_ * (OW_ / 4);  // 1,048,576
    const int block = 256;
    const int grid = n_threads / block;          // 4096
    maxnet_pool_kernel<<<grid, block, 0, stream>>>(x, out);
}